// Round 1
// baseline (601.551 us; speedup 1.0000x reference)
//
#include <hip/hip_runtime.h>
#include <cstdint>

#define BB 16
#define DD 64
#define LL 2048
#define NQ (BB*LL)        // 32768 queries
#define KK 8192           // codebook entries
#define VQ_SIZE (BB*DD*LL) // 2097152
#define CODE_BLOCKS 8
#define KPB (KK / CODE_BLOCKS)  // 1024

// ws layout: [0, NQ*8) packed keys (uint64), then KK*4 bytes of c2 floats.

__global__ __launch_bounds__(256) void vq_init(unsigned long long* __restrict__ keys,
                                               float* __restrict__ c2,
                                               const float* __restrict__ cb) {
    int t = blockIdx.x * 256 + threadIdx.x;
    if (t < NQ) keys[t] = 0xFFFFFFFFFFFFFFFFULL;
    if (t < KK) {
        const float4* c4 = (const float4*)(cb + t * DD);
        float s = 0.f;
        #pragma unroll
        for (int i = 0; i < DD/4; ++i) {
            float4 v = c4[i];
            s += v.x*v.x + v.y*v.y + v.z*v.z + v.w*v.w;
        }
        c2[t] = s;
    }
}

__global__ __launch_bounds__(256) void vq_dist(const float* __restrict__ ze,
                                               const float* __restrict__ cb,
                                               const float* __restrict__ c2,
                                               unsigned long long* __restrict__ keys) {
    const int q = blockIdx.x * 256 + threadIdx.x;   // query id
    const int b = q >> 11;          // q / LL
    const int l = q & (LL - 1);
    const float* zb = ze + b * (DD * LL) + l;

    // y[d] = -2 * x[d], held in VGPRs for the whole kernel
    float y[DD];
    #pragma unroll
    for (int d = 0; d < DD; ++d) y[d] = -2.0f * zb[d * LL];

    const int k0 = blockIdx.y * KPB;
    float best = 3.4e38f;
    int bidx = 0;

    for (int k = k0; k < k0 + KPB; ++k) {
        const float4* c4 = (const float4*)(cb + k * DD);   // wave-uniform -> scalar loads
        float acc = c2[k];
        #pragma unroll
        for (int i = 0; i < DD/4; ++i) {
            float4 v = c4[i];
            acc = fmaf(y[4*i+0], v.x, acc);
            acc = fmaf(y[4*i+1], v.y, acc);
            acc = fmaf(y[4*i+2], v.z, acc);
            acc = fmaf(y[4*i+3], v.w, acc);
        }
        if (acc < best) { best = acc; bidx = k; }   // strict < keeps lowest index on ties
    }

    // monotone float -> uint32 map (ascending), pack idx in low bits
    uint32_t ub = __float_as_uint(best);
    ub = (ub & 0x80000000u) ? ~ub : (ub | 0x80000000u);
    unsigned long long key = ((unsigned long long)ub << 32) | (unsigned)bidx;
    atomicMin(&keys[q], key);
}

__global__ __launch_bounds__(256) void vq_idx(const unsigned long long* __restrict__ keys,
                                              float* __restrict__ out_idx) {
    int q = blockIdx.x * 256 + threadIdx.x;
    if (q < NQ) out_idx[q] = (float)(unsigned)(keys[q] & 0xFFFFFFFFu);
}

__global__ __launch_bounds__(256) void vq_gather(const float* __restrict__ cb,
                                                 const float* __restrict__ idxf,
                                                 float* __restrict__ vq) {
    int t = blockIdx.x * 256 + threadIdx.x;   // flat index into v_q [B][D][L]
    int l = t & (LL - 1);
    int bd = t >> 11;        // b*64 + d
    int d = bd & 63;
    int b = bd >> 6;
    int idx = (int)idxf[b * LL + l];
    vq[t] = cb[idx * DD + d];                 // gather from L2-resident codebook
}

extern "C" void kernel_launch(void* const* d_in, const int* in_sizes, int n_in,
                              void* d_out, int out_size, void* d_ws, size_t ws_size,
                              hipStream_t stream) {
    const float* ze = (const float*)d_in[0];   // [B, D, L] f32
    const float* cb = (const float*)d_in[1];   // [K, D] f32
    float* out = (float*)d_out;                // [VQ_SIZE floats v_q][NQ floats indices]

    unsigned long long* keys = (unsigned long long*)d_ws;
    float* c2 = (float*)((char*)d_ws + (size_t)NQ * sizeof(unsigned long long));

    // 1. init keys + codebook norms
    vq_init<<<(NQ + KK + 255) / 256, 256, 0, stream>>>(keys, c2, cb);

    // 2. fused distance + argmin (atomicMin on packed key)
    dim3 g2(NQ / 256, CODE_BLOCKS);
    vq_dist<<<g2, 256, 0, stream>>>(ze, cb, c2, keys);

    // 3. unpack indices -> float32 region of d_out
    vq_idx<<<NQ / 256, 256, 0, stream>>>(keys, out + VQ_SIZE);

    // 4. gather codebook rows -> v_q (coalesced writes)
    vq_gather<<<VQ_SIZE / 256, 256, 0, stream>>>(cb, out + VQ_SIZE, out);
}